// Round 3
// baseline (186.261 us; speedup 1.0000x reference)
//
#include <hip/hip_runtime.h>
#include <math.h>

#define C_DIM 64
#define NEG_INF (-1e30f)
#define AW 132   // lds_a leading dim
#define BW 140   // lds_b leading dim (swizzled cols go up to 139)

// Single fused kernel: block-diagonal 4096x4096 masked-softmax contrastive
// loss. Grid 512 = 32 row-blocks(128) x 16 col-chunks(128) within the row's
// image. 2 blocks/CU. Each block: stage raw tiles -> in-block norms ->
// 128x128x64 register-tiled GEMM (8x8 micro) -> fused masked-softmax
// partials -> stats. Ticket: last block merges partials, writes scalar.
__global__ __launch_bounds__(256, 2) void fused_scl_kernel(
    const float* __restrict__ s, const float* __restrict__ t,
    const int* __restrict__ labels, float4* __restrict__ stats,
    unsigned int* __restrict__ ticket, float* __restrict__ out) {

    const int rb = blockIdx.x >> 4;          // 0..31 (row block of 128)
    const int jc = blockIdx.x & 15;          // 0..15 (col chunk of 128)
    const int img = rb >> 4;                 // 16 row-blocks per image
    const int i0 = rb * 128;
    const int jb = img * 2048 + jc * 128;

    const int tid = threadIdx.x;
    const int tx = tid & 15;
    const int ty = tid >> 4;

    __shared__ __align__(16) float lds_a[C_DIM][AW];
    __shared__ __align__(16) float lds_b[C_DIM][BW];
    __shared__ float lds_rs[128], lds_rt[128];
    __shared__ int lds_labi[128], lds_labj[128];
    __shared__ float red[3][256];
    __shared__ int lds_last;

    if (tid < 128) lds_labi[tid] = labels[i0 + tid];
    else           lds_labj[tid - 128] = labels[jb + tid - 128];

    // ---- stage raw A (rows) and B (cols) tiles, [c][pos], float4 ----
    {
        const int pos4 = (tid & 31) << 2;    // 0..124
        const int c0 = tid >> 5;             // 0..7
        const int bvi = ((i0 >> 10) << 16) + (i0 & 1023) + pos4;
        const int bvj = ((jb >> 10) << 16) + (jb & 1023) + pos4;
        const int sp = pos4 + ((pos4 >> 5) << 2);   // swizzled B offset
#pragma unroll
        for (int k = 0; k < 8; ++k) {
            int c = c0 + (k << 3);
            *(float4*)&lds_a[c][pos4] = *(const float4*)(s + bvi + c * 1024);
            *(float4*)&lds_b[c][sp]   = *(const float4*)(t + bvj + c * 1024);
        }
    }
    __syncthreads();

    // ---- in-block reciprocal norms (waves 0-1: rows, waves 2-3: cols) ----
    {
        const int p = tid & 127;
        float ssq = 0.f;
        if (tid < 128) {
#pragma unroll
            for (int c = 0; c < C_DIM; ++c) {
                float v = lds_a[c][p];
                ssq = fmaf(v, v, ssq);
            }
            lds_rs[p] = 1.f / fmaxf(sqrtf(ssq), 1e-12f);
        } else {
            const int sp = p + ((p >> 5) << 2);
#pragma unroll
            for (int c = 0; c < C_DIM; ++c) {
                float v = lds_b[c][sp];
                ssq = fmaf(v, v, ssq);
            }
            lds_rt[p] = 1.f / fmaxf(sqrtf(ssq), 1e-12f);
        }
    }
    __syncthreads();

    // ---- 128x128x64 GEMM, 8x8 per thread ----
    const int arow = ty << 3;
    const int bo = tx << 3;
    const int bos = bo + ((bo >> 5) << 2);

    float acc[8][8];
#pragma unroll
    for (int a = 0; a < 8; ++a)
#pragma unroll
        for (int b = 0; b < 8; ++b) acc[a][b] = 0.f;

#pragma unroll 4
    for (int c = 0; c < C_DIM; ++c) {
        float4 a0 = *(const float4*)&lds_a[c][arow];
        float4 a1 = *(const float4*)&lds_a[c][arow + 4];
        float4 b0 = *(const float4*)&lds_b[c][bos];
        float4 b1 = *(const float4*)&lds_b[c][bos + 4];
        const float ar[8] = {a0.x, a0.y, a0.z, a0.w, a1.x, a1.y, a1.z, a1.w};
        const float br[8] = {b0.x, b0.y, b0.z, b0.w, b1.x, b1.y, b1.z, b1.w};
#pragma unroll
        for (int a = 0; a < 8; ++a)
#pragma unroll
            for (int b = 0; b < 8; ++b)
                acc[a][b] = fmaf(ar[a], br[b], acc[a][b]);
    }

    // ---- fused epilogue: scale by rs_i*rt_j/T, mask, softmax partials ----
    int labi[8]; float rsi[8];
#pragma unroll
    for (int rr = 0; rr < 8; ++rr) {
        labi[rr] = lds_labi[arow + rr];
        rsi[rr] = lds_rs[arow + rr] * 10.f;   // fold 1/TEMPERATURE
    }
    int labj[8]; float rtj[8];
#pragma unroll
    for (int jj = 0; jj < 8; ++jj) {
        labj[jj] = lds_labj[bo + jj];
        rtj[jj] = lds_rt[bo + jj];
    }

    float m_run[8], s_run[8], A_run[8], c_run[8];
#pragma unroll
    for (int rr = 0; rr < 8; ++rr) {
        const int i_g = i0 + arow + rr;
        float vals[8];
        float lm = NEG_INF;
        float A = 0.f, cn = 0.f;
#pragma unroll
        for (int jj = 0; jj < 8; ++jj) {
            float logit = acc[rr][jj] * rsi[rr] * rtj[jj];
            bool self = ((jb + bo + jj) == i_g);
            float v = self ? NEG_INF : logit;
            vals[jj] = v;
            lm = fmaxf(lm, v);
            if (!self && labj[jj] == labi[rr]) { A += logit; cn += 1.f; }
        }
        float sn = 0.f;
#pragma unroll
        for (int jj = 0; jj < 8; ++jj) sn += __expf(vals[jj] - lm);
        m_run[rr] = lm; s_run[rr] = sn; A_run[rr] = A; c_run[rr] = cn;
    }

    // reduce across the 16 tx lanes (low 4 lane bits)
#pragma unroll
    for (int off = 1; off < 16; off <<= 1) {
#pragma unroll
        for (int rr = 0; rr < 8; ++rr) {
            float m2 = __shfl_xor(m_run[rr], off, 64);
            float s2 = __shfl_xor(s_run[rr], off, 64);
            float A2 = __shfl_xor(A_run[rr], off, 64);
            float c2 = __shfl_xor(c_run[rr], off, 64);
            float M = fmaxf(m_run[rr], m2);
            s_run[rr] = s_run[rr] * __expf(m_run[rr] - M) + s2 * __expf(m2 - M);
            m_run[rr] = M;
            A_run[rr] += A2;
            c_run[rr] += c2;
        }
    }

    if (tx == 0) {
#pragma unroll
        for (int rr = 0; rr < 8; ++rr)
            stats[(i0 + arow + rr) * 16 + jc] =
                make_float4(m_run[rr], s_run[rr], A_run[rr], c_run[rr]);
        __threadfence();   // make this thread's stats visible device-wide
    }
    __syncthreads();

    if (tid == 0) {
        unsigned int old = atomicAdd(ticket, 1u);
        lds_last = (old == 511u) ? 1 : 0;
    }
    __syncthreads();
    if (!lds_last) return;

    // ---- last block: merge 16 chunk partials per row, reduce loss ----
    __threadfence();   // acquire: see all other blocks' stats
    float sum_mlpp = 0.f, sum_valid = 0.f, sum_nbv = 0.f;
#pragma unroll 2
    for (int k = 0; k < 16; ++k) {
        const int r = tid + (k << 8);
        float m = NEG_INF, se = 0.f, A = 0.f, cnt = 0.f;
#pragma unroll
        for (int c = 0; c < 16; ++c) {
            float4 v = stats[r * 16 + c];
            float M = fmaxf(m, v.x);
            se = se * __expf(m - M) + v.y * __expf(v.x - M);
            m = M;
            A += v.z;
            cnt += v.w;
        }
        if (cnt > 0.5f) {   // integer count; > EPS <=> >= 1
            float lse = m + __logf(se);
            sum_mlpp += (A - cnt * lse) / (cnt + 1e-8f);
            sum_valid += 1.f;
            if (labels[r] != 0) sum_nbv += 1.f;
        }
    }
    red[0][tid] = sum_mlpp; red[1][tid] = sum_valid; red[2][tid] = sum_nbv;
    __syncthreads();
    for (int off = 128; off > 0; off >>= 1) {
        if (tid < off) {
            red[0][tid] += red[0][tid + off];
            red[1][tid] += red[1][tid + off];
            red[2][tid] += red[2][tid + off];
        }
        __syncthreads();
    }
    if (tid == 0) {
        float loss = -red[0][0] / red[1][0];
        float nbv = red[2][0];
        out[0] = loss * nbv / (nbv + 1e-8f);
    }
}

extern "C" void kernel_launch(void* const* d_in, const int* in_sizes, int n_in,
                              void* d_out, int out_size, void* d_ws, size_t ws_size,
                              hipStream_t stream) {
    const float* s = (const float*)d_in[0];
    const float* t = (const float*)d_in[1];
    const int* labels = (const int*)d_in[2];
    float* out = (float*)d_out;

    unsigned int* ticket = (unsigned int*)d_ws;         // 16 B (zeroed below)
    float4* stats = (float4*)((char*)d_ws + 16);        // 4096*16 float4 = 1 MB

    hipMemsetAsync(ticket, 0, 16, stream);
    hipLaunchKernelGGL(fused_scl_kernel, dim3(512), dim3(256), 0, stream,
                       s, t, labels, stats, ticket, out);
}

// Round 4
// 85.444 us; speedup vs baseline: 2.1799x; 2.1799x over previous
//
#include <hip/hip_runtime.h>
#include <math.h>

#define C_DIM 64
#define NEG_INF (-1e30f)
#define AW 132   // lds_a leading dim
#define BW 140   // lds_b leading dim (swizzled cols go up to 139)

// Main fused kernel: block-diagonal 4096x4096 masked-softmax contrastive
// loss partials. Grid 512 = 32 row-blocks(128) x 16 col-chunks(128) within
// the row's image; 2 blocks/CU (70 KB LDS). Stage raw tiles -> in-block
// norms -> 128x128x64 register-tiled GEMM (8x8 micro) -> fused
// masked-softmax partial stats. NO device-scope atomics/fences here
// (round-3 post-mortem: 512 same-line far-atomics serialized ~100us).
__global__ __launch_bounds__(256, 2) void fused_scl_kernel(
    const float* __restrict__ s, const float* __restrict__ t,
    const int* __restrict__ labels, float4* __restrict__ stats) {

    const int rb = blockIdx.x >> 4;          // 0..31 (row block of 128)
    const int jc = blockIdx.x & 15;          // 0..15 (col chunk of 128)
    const int img = rb >> 4;                 // 16 row-blocks per image
    const int i0 = rb * 128;
    const int jb = img * 2048 + jc * 128;

    const int tid = threadIdx.x;
    const int tx = tid & 15;
    const int ty = tid >> 4;

    __shared__ __align__(16) float lds_a[C_DIM][AW];
    __shared__ __align__(16) float lds_b[C_DIM][BW];
    __shared__ float lds_rs[128], lds_rt[128];
    __shared__ int lds_labi[128], lds_labj[128];

    if (tid < 128) lds_labi[tid] = labels[i0 + tid];
    else           lds_labj[tid - 128] = labels[jb + tid - 128];

    // ---- stage raw A (rows) and B (cols) tiles, [c][pos], float4 ----
    {
        const int pos4 = (tid & 31) << 2;    // 0..124
        const int c0 = tid >> 5;             // 0..7
        const int bvi = ((i0 >> 10) << 16) + (i0 & 1023) + pos4;
        const int bvj = ((jb >> 10) << 16) + (jb & 1023) + pos4;
        const int sp = pos4 + ((pos4 >> 5) << 2);   // swizzled B offset
#pragma unroll
        for (int k = 0; k < 8; ++k) {
            int c = c0 + (k << 3);
            *(float4*)&lds_a[c][pos4] = *(const float4*)(s + bvi + c * 1024);
            *(float4*)&lds_b[c][sp]   = *(const float4*)(t + bvj + c * 1024);
        }
    }
    __syncthreads();

    // ---- in-block reciprocal norms (threads 0-127: rows, 128-255: cols) ----
    {
        const int p = tid & 127;
        float ssq = 0.f;
        if (tid < 128) {
#pragma unroll
            for (int c = 0; c < C_DIM; ++c) {
                float v = lds_a[c][p];
                ssq = fmaf(v, v, ssq);
            }
            lds_rs[p] = 1.f / fmaxf(sqrtf(ssq), 1e-12f);
        } else {
            const int sp = p + ((p >> 5) << 2);
#pragma unroll
            for (int c = 0; c < C_DIM; ++c) {
                float v = lds_b[c][sp];
                ssq = fmaf(v, v, ssq);
            }
            lds_rt[p] = 1.f / fmaxf(sqrtf(ssq), 1e-12f);
        }
    }
    __syncthreads();

    // ---- 128x128x64 GEMM, 8x8 per thread ----
    const int arow = ty << 3;
    const int bo = tx << 3;
    const int bos = bo + ((bo >> 5) << 2);

    float acc[8][8];
#pragma unroll
    for (int a = 0; a < 8; ++a)
#pragma unroll
        for (int b = 0; b < 8; ++b) acc[a][b] = 0.f;

#pragma unroll 4
    for (int c = 0; c < C_DIM; ++c) {
        float4 a0 = *(const float4*)&lds_a[c][arow];
        float4 a1 = *(const float4*)&lds_a[c][arow + 4];
        float4 b0 = *(const float4*)&lds_b[c][bos];
        float4 b1 = *(const float4*)&lds_b[c][bos + 4];
        const float ar[8] = {a0.x, a0.y, a0.z, a0.w, a1.x, a1.y, a1.z, a1.w};
        const float br[8] = {b0.x, b0.y, b0.z, b0.w, b1.x, b1.y, b1.z, b1.w};
#pragma unroll
        for (int a = 0; a < 8; ++a)
#pragma unroll
            for (int b = 0; b < 8; ++b)
                acc[a][b] = fmaf(ar[a], br[b], acc[a][b]);
    }

    // ---- fused epilogue: scale by rs_i*rt_j/T, mask, softmax partials ----
    int labi[8]; float rsi[8];
#pragma unroll
    for (int rr = 0; rr < 8; ++rr) {
        labi[rr] = lds_labi[arow + rr];
        rsi[rr] = lds_rs[arow + rr] * 10.f;   // fold 1/TEMPERATURE
    }
    int labj[8]; float rtj[8];
#pragma unroll
    for (int jj = 0; jj < 8; ++jj) {
        labj[jj] = lds_labj[bo + jj];
        rtj[jj] = lds_rt[bo + jj];
    }

    float m_run[8], s_run[8], A_run[8], c_run[8];
#pragma unroll
    for (int rr = 0; rr < 8; ++rr) {
        const int i_g = i0 + arow + rr;
        float vals[8];
        float lm = NEG_INF;
        float A = 0.f, cn = 0.f;
#pragma unroll
        for (int jj = 0; jj < 8; ++jj) {
            float logit = acc[rr][jj] * rsi[rr] * rtj[jj];
            bool self = ((jb + bo + jj) == i_g);
            float v = self ? NEG_INF : logit;
            vals[jj] = v;
            lm = fmaxf(lm, v);
            if (!self && labj[jj] == labi[rr]) { A += logit; cn += 1.f; }
        }
        float sn = 0.f;
#pragma unroll
        for (int jj = 0; jj < 8; ++jj) sn += __expf(vals[jj] - lm);
        m_run[rr] = lm; s_run[rr] = sn; A_run[rr] = A; c_run[rr] = cn;
    }

    // reduce across the 16 tx lanes (low 4 lane bits)
#pragma unroll
    for (int off = 1; off < 16; off <<= 1) {
#pragma unroll
        for (int rr = 0; rr < 8; ++rr) {
            float m2 = __shfl_xor(m_run[rr], off, 64);
            float s2 = __shfl_xor(s_run[rr], off, 64);
            float A2 = __shfl_xor(A_run[rr], off, 64);
            float c2 = __shfl_xor(c_run[rr], off, 64);
            float M = fmaxf(m_run[rr], m2);
            s_run[rr] = s_run[rr] * __expf(m_run[rr] - M) + s2 * __expf(m2 - M);
            m_run[rr] = M;
            A_run[rr] += A2;
            c_run[rr] += c2;
        }
    }

    if (tx == 0) {
#pragma unroll
        for (int rr = 0; rr < 8; ++rr)
            stats[(i0 + arow + rr) * 16 + jc] =
                make_float4(m_run[rr], s_run[rr], A_run[rr], c_run[rr]);
    }
}

// -------- Finalize: merge 16 chunk partials per row, atomic global reduce ----
// 16 blocks -> only 48 far-atomics + 16 ticket atomics (proven cheap in R2).
__global__ __launch_bounds__(256) void finalize_kernel(
    const float4* __restrict__ stats, const int* __restrict__ labels,
    float* __restrict__ accums, float* __restrict__ out) {
    const int tid = threadIdx.x;
    const int r = blockIdx.x * 256 + tid;   // 16 blocks x 256 rows

    float m = NEG_INF, sexp = 0.f, A = 0.f, cnt = 0.f;
#pragma unroll
    for (int c = 0; c < 16; ++c) {
        float4 v = stats[r * 16 + c];
        float M = fmaxf(m, v.x);
        sexp = sexp * __expf(m - M) + v.y * __expf(v.x - M);
        m = M;
        A += v.z;
        cnt += v.w;
    }
    float mlpp = 0.f, val = 0.f, nbv = 0.f;
    if (cnt > 0.5f) {   // numerator count is an integer; > EPS  <=>  >= 1
        float lse = m + __logf(sexp);
        mlpp = (A - cnt * lse) / (cnt + 1e-8f);
        val = 1.f;
        nbv = (labels[r] != 0) ? 1.f : 0.f;
    }

    __shared__ float red0[256], red1[256], red2[256];
    red0[tid] = mlpp; red1[tid] = val; red2[tid] = nbv;
    __syncthreads();
    for (int off = 128; off > 0; off >>= 1) {
        if (tid < off) {
            red0[tid] += red0[tid + off];
            red1[tid] += red1[tid + off];
            red2[tid] += red2[tid + off];
        }
        __syncthreads();
    }

    if (tid == 0) {
        atomicAdd(&accums[0], red0[0]);
        atomicAdd(&accums[1], red1[0]);
        atomicAdd(&accums[2], red2[0]);
        __threadfence();
        unsigned int old = atomicAdd((unsigned int*)&accums[3], 1u);
        if (old == 15u) {   // last block: all adds visible
            float S = atomicAdd(&accums[0], 0.f);
            float V = atomicAdd(&accums[1], 0.f);
            float NB = atomicAdd(&accums[2], 0.f);
            float loss = -S / V;
            out[0] = loss * NB / (NB + 1e-8f);
        }
    }
}

extern "C" void kernel_launch(void* const* d_in, const int* in_sizes, int n_in,
                              void* d_out, int out_size, void* d_ws, size_t ws_size,
                              hipStream_t stream) {
    const float* s = (const float*)d_in[0];
    const float* t = (const float*)d_in[1];
    const int* labels = (const int*)d_in[2];
    float* out = (float*)d_out;

    float* accums = (float*)d_ws;                    // 32 B (zeroed below)
    float4* stats = (float4*)((char*)d_ws + 32);     // 4096*16 float4 = 1 MB

    hipMemsetAsync(accums, 0, 32, stream);
    hipLaunchKernelGGL(fused_scl_kernel, dim3(512), dim3(256), 0, stream,
                       s, t, labels, stats);
    hipLaunchKernelGGL(finalize_kernel, dim3(16), dim3(256), 0, stream,
                       stats, labels, accums, out);
}

// Round 5
// 74.197 us; speedup vs baseline: 2.5103x; 1.1516x over previous
//
#include <hip/hip_runtime.h>
#include <math.h>

#define NEG_INF (-1e30f)

typedef __attribute__((ext_vector_type(8))) short s16x8;   // 8 bf16 = 4 VGPRs (MFMA A/B frag)
typedef __attribute__((ext_vector_type(4))) float f32x4;   // MFMA C/D frag

// RNE float->bf16 pair pack (lo -> low short, hi -> high short)
__device__ __forceinline__ unsigned int pack_bf16(float lo, float hi) {
    unsigned int ul = __float_as_uint(lo);
    ul += 0x7FFFu + ((ul >> 16) & 1u);
    unsigned int uh = __float_as_uint(hi);
    uh += 0x7FFFu + ((uh >> 16) & 1u);
    return (ul >> 16) | (uh & 0xFFFF0000u);
}

// Fused kernel: block-diagonal 4096x4096 masked-softmax contrastive loss
// partials via bf16 MFMA. Grid 512 = 32 row-blocks(128) x 16 col-chunks(128)
// in-image; 2 blocks/CU (39 KB LDS). Phases: stage fp32->bf16 [pos][c] LDS
// (72-short stride: b128-aligned frags, balanced transpose writes) ->
// in-block norms from bf16 -> 16x16x32 MFMA (2 chained, K=64) -> fixed-max
// (logits<=10.2 so exp(l-10) is safe) masked-softmax partials -> stats.
__global__ __launch_bounds__(256, 2) void fused_scl_kernel(
    const float* __restrict__ s, const float* __restrict__ t,
    const int* __restrict__ labels, float4* __restrict__ stats,
    float* __restrict__ accums) {

    const int rb = blockIdx.x >> 4;          // row block of 128
    const int jc = blockIdx.x & 15;          // col chunk of 128
    const int img = rb >> 4;                 // 16 row-blocks per image
    const int i0 = rb * 128;
    const int jb = img * 2048 + jc * 128;

    const int tid = threadIdx.x;

    __shared__ __align__(16) short lds_a[128 * 72];   // [pos][c] bf16, stride 72
    __shared__ __align__(16) short lds_b[128 * 72];
    __shared__ float lds_rs[128], lds_rt[128];
    __shared__ int lds_labi[128], lds_labj[128];

    if (blockIdx.x == 0 && tid < 8) accums[tid] = 0.f;   // zero finalize accums

    if (tid < 128) lds_labi[tid] = labels[i0 + tid];
    else           lds_labj[tid - 128] = labels[jb + tid - 128];

    // ---- stage: global fp32 [c][pos] -> bf16 LDS [pos][c] ----
    {
        const int t7 = tid & 7;              // c-pair selector (write-bank spread)
        const int pos4 = (tid >> 3) << 2;    // 0..124
        const int bvi = ((i0 >> 10) << 16) + (i0 & 1023) + pos4;
        const int bvj = ((jb >> 10) << 16) + (jb & 1023) + pos4;
        unsigned int* wa = (unsigned int*)lds_a;
        unsigned int* wb = (unsigned int*)lds_b;
#pragma unroll
        for (int k = 0; k < 4; ++k) {
            const int c0 = 2 * t7 + 16 * k;
            float4 a0 = *(const float4*)(s + bvi + c0 * 1024);
            float4 a1 = *(const float4*)(s + bvi + (c0 + 1) * 1024);
            float4 b0 = *(const float4*)(t + bvj + c0 * 1024);
            float4 b1 = *(const float4*)(t + bvj + (c0 + 1) * 1024);
            const int w = t7 + 8 * k;        // word index within row (c0/2)
            wa[36 * (pos4 + 0) + w] = pack_bf16(a0.x, a1.x);
            wa[36 * (pos4 + 1) + w] = pack_bf16(a0.y, a1.y);
            wa[36 * (pos4 + 2) + w] = pack_bf16(a0.z, a1.z);
            wa[36 * (pos4 + 3) + w] = pack_bf16(a0.w, a1.w);
            wb[36 * (pos4 + 0) + w] = pack_bf16(b0.x, b1.x);
            wb[36 * (pos4 + 1) + w] = pack_bf16(b0.y, b1.y);
            wb[36 * (pos4 + 2) + w] = pack_bf16(b0.z, b1.z);
            wb[36 * (pos4 + 3) + w] = pack_bf16(b0.w, b1.w);
        }
    }
    __syncthreads();

    // ---- in-block reciprocal norms of the bf16-rounded vectors ----
    {
        const int row = tid & 127;
        const unsigned int* wr =
            (const unsigned int*)((tid < 128) ? lds_a : lds_b) + 36 * row;
        float ssq = 0.f;
#pragma unroll
        for (int i = 0; i < 8; ++i) {
            uint4 u4 = *(const uint4*)(wr + 4 * i);
            const unsigned int uu[4] = {u4.x, u4.y, u4.z, u4.w};
#pragma unroll
            for (int q = 0; q < 4; ++q) {
                float lo = __uint_as_float(uu[q] << 16);
                float hi = __uint_as_float(uu[q] & 0xFFFF0000u);
                ssq = fmaf(lo, lo, ssq);
                ssq = fmaf(hi, hi, ssq);
            }
        }
        float r = 1.f / fmaxf(sqrtf(ssq), 1e-12f);
        if (tid < 128) lds_rs[row] = r;
        else           lds_rt[row] = r;
    }
    __syncthreads();

    // ---- MFMA GEMM: per wave 32 rows x 128 cols ----
    const int lane = tid & 63;
    const int wv = tid >> 6;
    const int warow = wv << 5;
    const int quad = lane >> 4;
    const int col16 = lane & 15;

    s16x8 afr[2][2];
#pragma unroll
    for (int rt2 = 0; rt2 < 2; ++rt2) {
        const short* pa = lds_a + (warow + 16 * rt2 + col16) * 72 + 8 * quad;
        afr[rt2][0] = *(const s16x8*)pa;          // k = 0..31  (lane k = quad*8+j)
        afr[rt2][1] = *(const s16x8*)(pa + 32);   // k = 32..63
    }

    f32x4 acc[2][8];
#pragma unroll
    for (int ct = 0; ct < 8; ++ct) {
        const short* pb = lds_b + (16 * ct + col16) * 72 + 8 * quad;
        s16x8 blo = *(const s16x8*)pb;
        s16x8 bhi = *(const s16x8*)(pb + 32);
#pragma unroll
        for (int rt2 = 0; rt2 < 2; ++rt2) {
            f32x4 z = {0.f, 0.f, 0.f, 0.f};
            z = __builtin_amdgcn_mfma_f32_16x16x32_bf16(afr[rt2][0], blo, z, 0, 0, 0);
            z = __builtin_amdgcn_mfma_f32_16x16x32_bf16(afr[rt2][1], bhi, z, 0, 0, 0);
            acc[rt2][ct] = z;
        }
    }

    // ---- epilogue: scale, mask, fixed-max exp sums + numerator sums ----
    // C/D layout: col = lane&15, row = quad*4 + reg (verified m89/m91).
    float s_sum[8], A_sum[8], c_sum[8], rsi[8];
    int labi[8], ig[8];
#pragma unroll
    for (int rt2 = 0; rt2 < 2; ++rt2)
#pragma unroll
        for (int reg = 0; reg < 4; ++reg) {
            const int rr = rt2 * 4 + reg;
            const int rloc = warow + 16 * rt2 + 4 * quad + reg;
            rsi[rr] = lds_rs[rloc] * 10.f;       // fold 1/TEMPERATURE
            labi[rr] = lds_labi[rloc];
            ig[rr] = i0 + rloc;
            s_sum[rr] = 0.f; A_sum[rr] = 0.f; c_sum[rr] = 0.f;
        }

#pragma unroll
    for (int ct = 0; ct < 8; ++ct) {
        const int jg = jb + 16 * ct + col16;
        const float rtj = lds_rt[16 * ct + col16];
        const int lj = lds_labj[16 * ct + col16];
#pragma unroll
        for (int rt2 = 0; rt2 < 2; ++rt2)
#pragma unroll
            for (int reg = 0; reg < 4; ++reg) {
                const int rr = rt2 * 4 + reg;
                float logit = acc[rt2][ct][reg] * rsi[rr] * rtj;
                bool self = (jg == ig[rr]);
                float e = __expf((self ? NEG_INF : logit) - 10.f);  // <= e^0.3
                s_sum[rr] += e;
                if (!self && lj == labi[rr]) { A_sum[rr] += logit; c_sum[rr] += 1.f; }
            }
    }

    // plain-sum reduce across the 16 col lanes (low 4 lane bits)
#pragma unroll
    for (int off = 1; off < 16; off <<= 1)
#pragma unroll
        for (int rr = 0; rr < 8; ++rr) {
            s_sum[rr] += __shfl_xor(s_sum[rr], off, 64);
            A_sum[rr] += __shfl_xor(A_sum[rr], off, 64);
            c_sum[rr] += __shfl_xor(c_sum[rr], off, 64);
        }

    if (col16 == 0) {
#pragma unroll
        for (int rr = 0; rr < 8; ++rr)
            stats[ig[rr] * 16 + jc] =
                make_float4(s_sum[rr], A_sum[rr], c_sum[rr], 0.f);
    }
}

// -------- Finalize: sum 16 chunk partials per row, atomic global reduce ----
// Fixed-max semantics: lse = 10 + log(sum exp(l-10)). 16 blocks = 48 atomics.
__global__ __launch_bounds__(256) void finalize_kernel(
    const float4* __restrict__ stats, const int* __restrict__ labels,
    float* __restrict__ accums, float* __restrict__ out) {
    const int tid = threadIdx.x;
    const int r = blockIdx.x * 256 + tid;

    float ssum = 0.f, A = 0.f, cnt = 0.f;
#pragma unroll
    for (int c = 0; c < 16; ++c) {
        float4 v = stats[r * 16 + c];
        ssum += v.x; A += v.y; cnt += v.z;
    }
    float mlpp = 0.f, val = 0.f, nbv = 0.f;
    if (cnt > 0.5f) {   // integer count; > EPS <=> >= 1
        float lse = 10.f + __logf(ssum);
        mlpp = (A - cnt * lse) / (cnt + 1e-8f);
        val = 1.f;
        nbv = (labels[r] != 0) ? 1.f : 0.f;
    }

    __shared__ float red0[256], red1[256], red2[256];
    red0[tid] = mlpp; red1[tid] = val; red2[tid] = nbv;
    __syncthreads();
    for (int off = 128; off > 0; off >>= 1) {
        if (tid < off) {
            red0[tid] += red0[tid + off];
            red1[tid] += red1[tid + off];
            red2[tid] += red2[tid + off];
        }
        __syncthreads();
    }

    if (tid == 0) {
        atomicAdd(&accums[0], red0[0]);
        atomicAdd(&accums[1], red1[0]);
        atomicAdd(&accums[2], red2[0]);
        __threadfence();
        unsigned int old = atomicAdd((unsigned int*)&accums[3], 1u);
        if (old == 15u) {
            float S = atomicAdd(&accums[0], 0.f);
            float V = atomicAdd(&accums[1], 0.f);
            float NB = atomicAdd(&accums[2], 0.f);
            float loss = -S / V;
            out[0] = loss * NB / (NB + 1e-8f);
        }
    }
}

extern "C" void kernel_launch(void* const* d_in, const int* in_sizes, int n_in,
                              void* d_out, int out_size, void* d_ws, size_t ws_size,
                              hipStream_t stream) {
    const float* s = (const float*)d_in[0];
    const float* t = (const float*)d_in[1];
    const int* labels = (const int*)d_in[2];
    float* out = (float*)d_out;

    float* accums = (float*)d_ws;                   // 32 B, zeroed by block 0
    float4* stats = (float4*)((char*)d_ws + 32);    // 4096*16 float4 = 1 MB

    hipLaunchKernelGGL(fused_scl_kernel, dim3(512), dim3(256), 0, stream,
                       s, t, labels, stats, accums);
    hipLaunchKernelGGL(finalize_kernel, dim3(16), dim3(256), 0, stream,
                       stats, labels, accums, out);
}